// Round 5
// baseline (1696.523 us; speedup 1.0000x reference)
//
#include <hip/hip_runtime.h>

#define S_LEN 2048
#define D_DIM 128
#define BQ 128
#define BK 32
#define NITER (S_LEN / BK)   // 64
#define NITER2 (NITER / 2)   // 32 iterations, 2 tiles each (even/odd wave-sets)

typedef float f32x4 __attribute__((ext_vector_type(4)));
typedef short s16x8 __attribute__((ext_vector_type(8)));
typedef short s16x4 __attribute__((ext_vector_type(4)));
typedef unsigned int u32;

#if __has_builtin(__builtin_amdgcn_exp2f)
#define EXP2(x) __builtin_amdgcn_exp2f(x)
#else
#define EXP2(x) exp2f(x)
#endif

// pack two floats' bf16 into one u32: x0 in lower 16, x1 in upper 16
__device__ __forceinline__ u32 pack_trunc(float x0, float x1) {
    return __builtin_amdgcn_perm(__float_as_uint(x1), __float_as_uint(x0), 0x07060302u);
}
__device__ __forceinline__ u32 pack_rne(float x0, float x1) {
    return __builtin_amdgcn_perm(__float_as_uint(x1) + 0x8000u,
                                 __float_as_uint(x0) + 0x8000u, 0x07060302u);
}

#define GLOAD16(g, l) \
    __builtin_amdgcn_global_load_lds((const __attribute__((address_space(1))) u32*)(g), \
                                     (__attribute__((address_space(3))) u32*)(l), 16, 0, 0)

// K=16 bf16 MFMA: A/B frag = 4 bf16 (lane: elem k = quad*4 + j), C/D = f32x4.
#if __has_builtin(__builtin_amdgcn_mfma_f32_16x16x16bf16_1k)
__device__ __forceinline__ f32x4 MFMA16(s16x4 a, s16x4 b, f32x4 c) {
    return __builtin_amdgcn_mfma_f32_16x16x16bf16_1k(a, b, c, 0, 0, 0);
}
#else
__device__ __forceinline__ f32x4 MFMA16(s16x4 a, s16x4 b, f32x4 c) {
    asm("v_mfma_f32_16x16x16_bf16 %0, %1, %2, %0" : "+v"(c) : "v"(a), "v"(b));
    return c;
}
#endif

// ---- butterfly over lanes {l, l^16, l^32, l^48} on the VALU pipe (gfx950 permlane swaps).
#if __has_builtin(__builtin_amdgcn_permlane16_swap) && __has_builtin(__builtin_amdgcn_permlane32_swap)
#define BFLY(x, OP)                                                                       \
    {                                                                                     \
        auto p_ = __builtin_amdgcn_permlane16_swap(__float_as_uint(x), __float_as_uint(x), false, false); \
        x = OP(__uint_as_float(p_[0]), __uint_as_float(p_[1]));                           \
        auto q_ = __builtin_amdgcn_permlane32_swap(__float_as_uint(x), __float_as_uint(x), false, false); \
        x = OP(__uint_as_float(q_[0]), __uint_as_float(q_[1]));                           \
    }
#else
#define BFLY(x, OP)                      \
    {                                    \
        x = OP(x, __shfl_xor(x, 16));    \
        x = OP(x, __shfl_xor(x, 32));    \
    }
#endif
__device__ __forceinline__ float fadd_(float a, float b) { return a + b; }

// ---------------- pre-pass: K -> hi/lo bf16, tiled + XOR-swizzled 16B units ----------------
// Kc layout: [bh][kt][r=0..31][u'=0..31][8 ushorts]; u = 2c (hi) / 2c+1 (lo); u' = u ^ (r&7).
__global__ void prep_k(const float* __restrict__ K, unsigned short* __restrict__ Kc) {
    const int t  = blockIdx.x * 256 + threadIdx.x;   // 2^20 threads
    const int c  = t & 15;
    const int s  = (t >> 4) & (S_LEN - 1);
    const int bh = t >> 15;
    const float* src = K + ((size_t)bh * S_LEN + s) * D_DIM + c * 8;
    const float4 a = *(const float4*)src;
    const float4 b = *(const float4*)(src + 4);
    const float x[8] = {a.x,a.y,a.z,a.w,b.x,b.y,b.z,b.w};
    u32 h[4], l[4];
    #pragma unroll
    for (int i = 0; i < 4; ++i) {
        const float x0 = x[2*i], x1 = x[2*i+1];
        h[i] = pack_trunc(x0, x1);
        const float r0 = x0 - __uint_as_float(__float_as_uint(x0) & 0xFFFF0000u);
        const float r1 = x1 - __uint_as_float(__float_as_uint(x1) & 0xFFFF0000u);
        l[i] = pack_trunc(r0, r1);
    }
    const int kt = s >> 5, r = s & 31, rl = r & 7;
    unsigned short* base = Kc + ((((size_t)bh * NITER + kt) * 32 + r) << 8);
    *(uint4*)(base + (((2*c)     ^ rl) << 3)) = make_uint4(h[0],h[1],h[2],h[3]);
    *(uint4*)(base + (((2*c + 1) ^ rl) << 3)) = make_uint4(l[0],l[1],l[2],l[3]);
}

// ---------------- pre-pass: V -> per-lane PV fragment chunks ----------------
// Vt[bh][kt][dt(8)][lane(64)][8 ushorts]: for lane = quad*16+lr,
//   elems 0..3 = bf16(V[kt*32 +    quad*4 + j][dt*16 + lr])  (va0)
//   elems 4..7 = bf16(V[kt*32 + 16 + quad*4 + j][dt*16 + lr])  (va1)
__global__ void prep_v(const float* __restrict__ V, unsigned short* __restrict__ Vt) {
    const int t  = blockIdx.x * 256 + threadIdx.x;   // 2^18 threads: (bh, kt, d)
    const int d  = t & 127;
    const int kt = (t >> 7) & (NITER - 1);
    const int bh = t >> 13;
    const float* src = V + (((size_t)bh * NITER + kt) * BK) * D_DIM + d;
    const int dt = d >> 4, lr = d & 15;
    unsigned short* base = Vt + ((((size_t)bh * NITER + kt) * 8 + dt) << 9);
    #pragma unroll
    for (int q = 0; q < 4; ++q) {
        u32 w0 = pack_rne(src[(q*4+0) * D_DIM],    src[(q*4+1) * D_DIM]);
        u32 w1 = pack_rne(src[(q*4+2) * D_DIM],    src[(q*4+3) * D_DIM]);
        u32 w2 = pack_rne(src[(16+q*4+0) * D_DIM], src[(16+q*4+1) * D_DIM]);
        u32 w3 = pack_rne(src[(16+q*4+2) * D_DIM], src[(16+q*4+3) * D_DIM]);
        *(uint4*)(base + ((q * 16 + lr) << 3)) = make_uint4(w0, w1, w2, w3);
    }
}

// ---------------- hot kernel: split-kt over two 4-wave sets, 4 waves/SIMD ----------------
// Waves 0-3 process even K-tiles, waves 4-7 odd K-tiles (same 128 q-rows);
// private (m,l,O) merged in a flash-style two-way epilogue.
__global__ __launch_bounds__(512, 4)
void attn_fused(const float* __restrict__ Q, const unsigned short* __restrict__ Kc,
                const unsigned short* __restrict__ Vt, const float* __restrict__ SF,
                const int* __restrict__ DP, float* __restrict__ OUT)
{
    __shared__ __align__(16) unsigned short sK[2][2][32 * 256];  // [buf][parity] 4 x 16 KB
    __shared__ float mlx[4][2][16][2];                           // 1 KB m/l exchange

    const int bh   = blockIdx.y;
    const int q0   = blockIdx.x * BQ;
    const int tid  = threadIdx.x;
    const int w    = tid >> 6;
    const int par  = w >> 2;         // 0: even tiles, 1: odd tiles
    const int wq   = w & 3;          // q-group within block
    const int lane = tid & 63;
    const int quad = lane >> 4;
    const int lr   = lane & 15;
    const int rl   = lr & 7;

    const size_t bh_off = (size_t)bh * S_LEN * D_DIM;
    const float LOG2E = 1.4426950408889634f;

    // ---- Q fragments for 2 q-groups, hi/lo bf16 split ----
    s16x8 qhi[2][4], qlo[2][4];
    int qrow[2];
    #pragma unroll
    for (int g = 0; g < 2; ++g) {
        qrow[g] = q0 + wq * 32 + g * 16 + lr;
        const float* qr = Q + bh_off + (size_t)qrow[g] * D_DIM + quad * 8;
        #pragma unroll
        for (int d0 = 0; d0 < 4; ++d0) {
            const float4 u0 = *(const float4*)(qr + d0 * 32);
            const float4 u1 = *(const float4*)(qr + d0 * 32 + 4);
            const float x[8] = {u0.x,u0.y,u0.z,u0.w,u1.x,u1.y,u1.z,u1.w};
            union { u32 w4[4]; s16x8 v; } H, L;
            #pragma unroll
            for (int i = 0; i < 4; ++i) {
                const float x0 = x[2*i], x1 = x[2*i+1];
                H.w4[i] = pack_trunc(x0, x1);
                const float r0 = x0 - __uint_as_float(__float_as_uint(x0) & 0xFFFF0000u);
                const float r1 = x1 - __uint_as_float(__float_as_uint(x1) & 0xFFFF0000u);
                L.w4[i] = pack_trunc(r0, r1);
            }
            qhi[g][d0] = H.v; qlo[g][d0] = L.v;
        }
    }

    // O^T accumulators: Oacc[g][dt][r] = O[q=qrow[g]][d = dt*16 + quad*4 + r]
    f32x4 Oacc[2][8] = {};
    float mrow[2] = {-INFINITY, -INFINITY};
    float lrow[2] = {0.f, 0.f};

    const unsigned short* KtBase = Kc + (((size_t)bh * NITER) << 13);
    const unsigned short* VtBase = Vt + (((size_t)bh * NITER) << 12) + (lane << 3);

    // ---- prologue: DMA tile (par) -> buf 0; SF tile (par) -> regs ----
    {
        const unsigned short* K0 = KtBase + ((size_t)par << 13);
        #pragma unroll
        for (int i = 0; i < 4; ++i)
            GLOAD16(K0 + (wq * 4 + i) * 512 + lane * 8, &sK[0][par][(wq * 4 + i) * 512]);
    }

    const float* sfq[2];
    f32x4 sf0[2], sf1[2];
    {
        const f32x4 l2e = {LOG2E, LOG2E, LOG2E, LOG2E};
        #pragma unroll
        for (int g = 0; g < 2; ++g) {
            sfq[g] = SF + (size_t)qrow[g] * S_LEN + quad * 4;
            sf0[g] = *(const f32x4*)(sfq[g] + par * 32) * l2e;
            sf1[g] = *(const f32x4*)(sfq[g] + par * 32 + 16) * l2e;
        }
    }

    for (int it = 0; it < NITER2; ++it) {
        const int p = it & 1;
        // Publishes sK[p][*] (vmcnt(0) drain: DMAs issued a full iteration ago).
        // Also guarantees everyone is done reading sK[1-p][*].
        __syncthreads();

        // ---- V(2*it+par) -> registers, issued first (consumed after QK+softmax) ----
        uint4 vreg[8];
        {
            const unsigned short* Vk = VtBase + ((size_t)(2 * it + par) << 12);
            #pragma unroll
            for (int dt = 0; dt < 8; ++dt)
                vreg[dt] = *(const uint4*)(Vk + (dt << 9));
        }

        // ---- prefetch tile (2*it+2+par) into buf[1-p][par]; SF into regs ----
        f32x4 nf0[2], nf1[2];
        const bool more = (it + 1 < NITER2);
        if (more) {
            const unsigned short* Kn = KtBase + ((size_t)(2 * it + 2 + par) << 13);
            #pragma unroll
            for (int i = 0; i < 4; ++i)
                GLOAD16(Kn + (wq * 4 + i) * 512 + lane * 8, &sK[1 - p][par][(wq * 4 + i) * 512]);
            const f32x4 l2e = {LOG2E, LOG2E, LOG2E, LOG2E};
            #pragma unroll
            for (int g = 0; g < 2; ++g) {
                nf0[g] = *(const f32x4*)(sfq[g] + (2 * it + 2 + par) * 32) * l2e;
                nf1[g] = *(const f32x4*)(sfq[g] + (2 * it + 2 + par) * 32 + 16) * l2e;
            }
        }

        // ---- QK^T, swapped operands; each K fragment reused by both q-groups ----
        const unsigned short* sKp = sK[p][par];
        f32x4 acc[2][2] = {};
        __builtin_amdgcn_s_setprio(1);
        #pragma unroll
        for (int nt = 0; nt < 2; ++nt) {
            const unsigned short* rowp = sKp + (nt * 16 + lr) * 256;
            #pragma unroll
            for (int d0 = 0; d0 < 4; ++d0) {
                const int uh = (8 * d0 + 2 * quad) ^ rl;
                const s16x8 kh8 = *(const s16x8*)(rowp + (uh << 3));
                const s16x8 kl8 = *(const s16x8*)(rowp + ((uh ^ 1) << 3));
                #pragma unroll
                for (int g = 0; g < 2; ++g) {
                    acc[g][nt] = __builtin_amdgcn_mfma_f32_16x16x32_bf16(kh8, qlo[g][d0], acc[g][nt], 0, 0, 0);
                    acc[g][nt] = __builtin_amdgcn_mfma_f32_16x16x32_bf16(kl8, qhi[g][d0], acc[g][nt], 0, 0, 0);
                    acc[g][nt] = __builtin_amdgcn_mfma_f32_16x16x32_bf16(kh8, qhi[g][d0], acc[g][nt], 0, 0, 0);
                }
            }
        }
        __builtin_amdgcn_s_setprio(0);

        // ---- online softmax (base-2), lane-local rows + VALU butterflies ----
        union PB { u32 w2[2]; s16x4 v; } B0[2], B1[2];
        #pragma unroll
        for (int g = 0; g < 2; ++g) {
            const f32x4 t0 = acc[g][0] * sf0[g];
            const f32x4 t1 = acc[g][1] * sf1[g];
            float mx = fmaxf(fmaxf(fmaxf(t0[0], t0[1]), fmaxf(t0[2], t0[3])),
                             fmaxf(fmaxf(t1[0], t1[1]), fmaxf(t1[2], t1[3])));
            BFLY(mx, fmaxf);
            const float mnew = fmaxf(mrow[g], mx);
            if (!__all(mnew == mrow[g])) {
                const float al = EXP2(mrow[g] - mnew);
                mrow[g] = mnew;
                lrow[g] *= al;
                const f32x4 alv = {al, al, al, al};
                #pragma unroll
                for (int dt = 0; dt < 8; ++dt)
                    Oacc[g][dt] *= alv;
            }
            const float m = mrow[g];
            f32x4 P0, P1;
            #pragma unroll
            for (int r = 0; r < 4; ++r) {
                P0[r] = EXP2(t0[r] - m);
                P1[r] = EXP2(t1[r] - m);
            }
            float rs = ((P0[0] + P0[1]) + (P0[2] + P0[3])) + ((P1[0] + P1[1]) + (P1[2] + P1[3]));
            BFLY(rs, fadd_);
            lrow[g] += rs;
            B0[g].w2[0] = pack_rne(P0[0], P0[1]); B0[g].w2[1] = pack_rne(P0[2], P0[3]);
            B1[g].w2[0] = pack_rne(P1[0], P1[1]); B1[g].w2[1] = pack_rne(P1[2], P1[3]);
        }

        // ---- P·V from registers; each V fragment reused by both q-groups ----
        __builtin_amdgcn_s_setprio(1);
        #pragma unroll
        for (int dt = 0; dt < 8; ++dt) {
            union { uint4 u; struct { s16x4 a0; s16x4 a1; } s; } vv;
            vv.u = vreg[dt];
            #pragma unroll
            for (int g = 0; g < 2; ++g) {
                Oacc[g][dt] = MFMA16(vv.s.a0, B0[g].v, Oacc[g][dt]);
                Oacc[g][dt] = MFMA16(vv.s.a1, B1[g].v, Oacc[g][dt]);
            }
        }
        __builtin_amdgcn_s_setprio(0);

        if (more) {
            #pragma unroll
            for (int g = 0; g < 2; ++g) { sf0[g] = nf0[g]; sf1[g] = nf1[g]; }
        }
    }

    // ---- epilogue: two-way flash merge (even set combines, odd set publishes) ----
    __syncthreads();   // all K-tile reads done; sK reusable as O buffer
    float* obuf = (float*)&sK[0][0][0];   // 64 KB: [wq][g][dt][lane] f32x4
    if (par) {
        #pragma unroll
        for (int g = 0; g < 2; ++g) {
            mlx[wq][g][lr][0] = mrow[g];   // replicated across quads: same value
            mlx[wq][g][lr][1] = lrow[g];
            #pragma unroll
            for (int dt = 0; dt < 8; ++dt)
                *(f32x4*)(obuf + ((((wq * 2 + g) * 8 + dt) * 64 + lane) << 2)) = Oacc[g][dt];
        }
    }
    __syncthreads();
    if (!par) {
        const float dpf = (float)DP[0];
        #pragma unroll
        for (int g = 0; g < 2; ++g) {
            const float m_o = mlx[wq][g][lr][0];
            const float l_o = mlx[wq][g][lr][1];
            const float ms  = fmaxf(mrow[g], m_o);
            const float se  = EXP2(mrow[g] - ms);
            const float so  = EXP2(m_o - ms);
            const float ls  = se * lrow[g] + so * l_o;
            const float fe  = se * dpf / ls;
            const float fo  = so * dpf / ls;
            const f32x4 fev = {fe, fe, fe, fe};
            const f32x4 fov = {fo, fo, fo, fo};
            float* orow = OUT + bh_off + (size_t)qrow[g] * D_DIM + quad * 4;
            #pragma unroll
            for (int dt = 0; dt < 8; ++dt) {
                const f32x4 oo = *(const f32x4*)(obuf + ((((wq * 2 + g) * 8 + dt) * 64 + lane) << 2));
                const f32x4 o = Oacc[g][dt] * fev + oo * fov;
                *(f32x4*)(orow + dt * 16) = o;
            }
        }
    }
}

extern "C" void kernel_launch(void* const* d_in, const int* in_sizes, int n_in,
                              void* d_out, int out_size, void* d_ws, size_t ws_size,
                              hipStream_t stream) {
    const float* q  = (const float*)d_in[0];
    const float* k  = (const float*)d_in[1];
    const float* v  = (const float*)d_in[2];
    const float* sf = (const float*)d_in[3];
    const int*   dp = (const int*)d_in[4];
    float* out = (float*)d_out;

    const size_t kc_ushorts = (size_t)32 * NITER * 32 * 256;
    unsigned short* Kc = (unsigned short*)d_ws;
    unsigned short* Vt = Kc + kc_ushorts;

    prep_k<<<4096, 256, 0, stream>>>(k, Kc);
    prep_v<<<1024, 256, 0, stream>>>(v, Vt);
    dim3 grid(S_LEN / BQ, 32);   // (16, 32) = 512 blocks of 512 threads, 2/CU
    attn_fused<<<grid, dim3(512), 0, stream>>>(q, Kc, Vt, sf, dp, out);
}

// Round 6
// 382.803 us; speedup vs baseline: 4.4318x; 4.4318x over previous
//
#include <hip/hip_runtime.h>

#define S_LEN 2048
#define D_DIM 128
#define BQ 128
#define BK 32
#define NITER (S_LEN / BK)   // 64
#define NITER2 (NITER / 2)   // 32 iterations, 2 tiles each (even/odd wave-sets)

typedef float f32x4 __attribute__((ext_vector_type(4)));
typedef short s16x8 __attribute__((ext_vector_type(8)));
typedef short s16x4 __attribute__((ext_vector_type(4)));
typedef unsigned int u32;

#if __has_builtin(__builtin_amdgcn_exp2f)
#define EXP2(x) __builtin_amdgcn_exp2f(x)
#else
#define EXP2(x) exp2f(x)
#endif

// pack two floats' bf16 into one u32: x0 in lower 16, x1 in upper 16
__device__ __forceinline__ u32 pack_trunc(float x0, float x1) {
    return __builtin_amdgcn_perm(__float_as_uint(x1), __float_as_uint(x0), 0x07060302u);
}
__device__ __forceinline__ u32 pack_rne(float x0, float x1) {
    return __builtin_amdgcn_perm(__float_as_uint(x1) + 0x8000u,
                                 __float_as_uint(x0) + 0x8000u, 0x07060302u);
}

#define GLOAD16(g, l) \
    __builtin_amdgcn_global_load_lds((const __attribute__((address_space(1))) u32*)(g), \
                                     (__attribute__((address_space(3))) u32*)(l), 16, 0, 0)

// K=16 bf16 MFMA: A/B frag = 4 bf16 (lane: elem k = quad*4 + j), C/D = f32x4.
#if __has_builtin(__builtin_amdgcn_mfma_f32_16x16x16bf16_1k)
__device__ __forceinline__ f32x4 MFMA16(s16x4 a, s16x4 b, f32x4 c) {
    return __builtin_amdgcn_mfma_f32_16x16x16bf16_1k(a, b, c, 0, 0, 0);
}
#else
__device__ __forceinline__ f32x4 MFMA16(s16x4 a, s16x4 b, f32x4 c) {
    asm("v_mfma_f32_16x16x16_bf16 %0, %1, %2, %0" : "+v"(c) : "v"(a), "v"(b));
    return c;
}
#endif

// ---- butterfly over lanes {l, l^16, l^32, l^48} on the VALU pipe (gfx950 permlane swaps).
#if __has_builtin(__builtin_amdgcn_permlane16_swap) && __has_builtin(__builtin_amdgcn_permlane32_swap)
#define BFLY(x, OP)                                                                       \
    {                                                                                     \
        auto p_ = __builtin_amdgcn_permlane16_swap(__float_as_uint(x), __float_as_uint(x), false, false); \
        x = OP(__uint_as_float(p_[0]), __uint_as_float(p_[1]));                           \
        auto q_ = __builtin_amdgcn_permlane32_swap(__float_as_uint(x), __float_as_uint(x), false, false); \
        x = OP(__uint_as_float(q_[0]), __uint_as_float(q_[1]));                           \
    }
#else
#define BFLY(x, OP)                      \
    {                                    \
        x = OP(x, __shfl_xor(x, 16));    \
        x = OP(x, __shfl_xor(x, 32));    \
    }
#endif
__device__ __forceinline__ float fadd_(float a, float b) { return a + b; }

// ---------------- pre-pass: K -> hi/lo bf16, tiled + XOR-swizzled 16B units ----------------
// Kc layout: [bh][kt][r=0..31][u'=0..31][8 ushorts]; u = 2c (hi) / 2c+1 (lo); u' = u ^ (r&7).
__global__ void prep_k(const float* __restrict__ K, unsigned short* __restrict__ Kc) {
    const int t  = blockIdx.x * 256 + threadIdx.x;   // 2^20 threads
    const int c  = t & 15;
    const int s  = (t >> 4) & (S_LEN - 1);
    const int bh = t >> 15;
    const float* src = K + ((size_t)bh * S_LEN + s) * D_DIM + c * 8;
    const float4 a = *(const float4*)src;
    const float4 b = *(const float4*)(src + 4);
    const float x[8] = {a.x,a.y,a.z,a.w,b.x,b.y,b.z,b.w};
    u32 h[4], l[4];
    #pragma unroll
    for (int i = 0; i < 4; ++i) {
        const float x0 = x[2*i], x1 = x[2*i+1];
        h[i] = pack_trunc(x0, x1);
        const float r0 = x0 - __uint_as_float(__float_as_uint(x0) & 0xFFFF0000u);
        const float r1 = x1 - __uint_as_float(__float_as_uint(x1) & 0xFFFF0000u);
        l[i] = pack_trunc(r0, r1);
    }
    const int kt = s >> 5, r = s & 31, rl = r & 7;
    unsigned short* base = Kc + ((((size_t)bh * NITER + kt) * 32 + r) << 8);
    *(uint4*)(base + (((2*c)     ^ rl) << 3)) = make_uint4(h[0],h[1],h[2],h[3]);
    *(uint4*)(base + (((2*c + 1) ^ rl) << 3)) = make_uint4(l[0],l[1],l[2],l[3]);
}

// ---------------- pre-pass: V -> per-lane PV fragment chunks ----------------
// Vt[bh][kt][dt(8)][lane(64)][8 ushorts]: for lane = quad*16+lr,
//   elems 0..3 = bf16(V[kt*32 +    quad*4 + j][dt*16 + lr])  (va0)
//   elems 4..7 = bf16(V[kt*32 + 16 + quad*4 + j][dt*16 + lr])  (va1)
__global__ void prep_v(const float* __restrict__ V, unsigned short* __restrict__ Vt) {
    const int t  = blockIdx.x * 256 + threadIdx.x;   // 2^18 threads: (bh, kt, d)
    const int d  = t & 127;
    const int kt = (t >> 7) & (NITER - 1);
    const int bh = t >> 13;
    const float* src = V + (((size_t)bh * NITER + kt) * BK) * D_DIM + d;
    const int dt = d >> 4, lr = d & 15;
    unsigned short* base = Vt + ((((size_t)bh * NITER + kt) * 8 + dt) << 9);
    #pragma unroll
    for (int q = 0; q < 4; ++q) {
        u32 w0 = pack_rne(src[(q*4+0) * D_DIM],    src[(q*4+1) * D_DIM]);
        u32 w1 = pack_rne(src[(q*4+2) * D_DIM],    src[(q*4+3) * D_DIM]);
        u32 w2 = pack_rne(src[(16+q*4+0) * D_DIM], src[(16+q*4+1) * D_DIM]);
        u32 w3 = pack_rne(src[(16+q*4+2) * D_DIM], src[(16+q*4+3) * D_DIM]);
        *(uint4*)(base + ((q * 16 + lr) << 3)) = make_uint4(w0, w1, w2, w3);
    }
}

// ---------------- hot kernel: split-kt over two 4-wave sets ----------------
// Waves 0-3 process even K-tiles, waves 4-7 odd K-tiles (same 128 q-rows);
// private (m,l,O) merged in a flash-style two-way epilogue.
// __launch_bounds__(512, 2): 2 blocks/CU -> 16 waves/CU -> VGPR cap 128.
// (R5's (512,4) capped VGPR at 64 -> catastrophic scratch spill, 3.3 GB FETCH.)
__global__ __launch_bounds__(512, 2)
void attn_fused(const float* __restrict__ Q, const unsigned short* __restrict__ Kc,
                const unsigned short* __restrict__ Vt, const float* __restrict__ SF,
                const int* __restrict__ DP, float* __restrict__ OUT)
{
    __shared__ __align__(16) unsigned short sK[2][2][32 * 256];  // [buf][parity] 4 x 16 KB
    __shared__ float mlx[4][2][16][2];                           // 1 KB m/l exchange

    const int bh   = blockIdx.y;
    const int q0   = blockIdx.x * BQ;
    const int tid  = threadIdx.x;
    const int w    = tid >> 6;
    const int par  = w >> 2;         // 0: even tiles, 1: odd tiles
    const int wq   = w & 3;          // q-group within block
    const int lane = tid & 63;
    const int quad = lane >> 4;
    const int lr   = lane & 15;
    const int rl   = lr & 7;

    const size_t bh_off = (size_t)bh * S_LEN * D_DIM;
    const float LOG2E = 1.4426950408889634f;

    // ---- Q fragments for 2 q-groups, hi/lo bf16 split ----
    s16x8 qhi[2][4], qlo[2][4];
    int qrow[2];
    #pragma unroll
    for (int g = 0; g < 2; ++g) {
        qrow[g] = q0 + wq * 32 + g * 16 + lr;
        const float* qr = Q + bh_off + (size_t)qrow[g] * D_DIM + quad * 8;
        #pragma unroll
        for (int d0 = 0; d0 < 4; ++d0) {
            const float4 u0 = *(const float4*)(qr + d0 * 32);
            const float4 u1 = *(const float4*)(qr + d0 * 32 + 4);
            const float x[8] = {u0.x,u0.y,u0.z,u0.w,u1.x,u1.y,u1.z,u1.w};
            union { u32 w4[4]; s16x8 v; } H, L;
            #pragma unroll
            for (int i = 0; i < 4; ++i) {
                const float x0 = x[2*i], x1 = x[2*i+1];
                H.w4[i] = pack_trunc(x0, x1);
                const float r0 = x0 - __uint_as_float(__float_as_uint(x0) & 0xFFFF0000u);
                const float r1 = x1 - __uint_as_float(__float_as_uint(x1) & 0xFFFF0000u);
                L.w4[i] = pack_trunc(r0, r1);
            }
            qhi[g][d0] = H.v; qlo[g][d0] = L.v;
        }
    }

    // O^T accumulators: Oacc[g][dt][r] = O[q=qrow[g]][d = dt*16 + quad*4 + r]
    f32x4 Oacc[2][8] = {};
    float mrow[2] = {-INFINITY, -INFINITY};
    float lrow[2] = {0.f, 0.f};

    const unsigned short* KtBase = Kc + (((size_t)bh * NITER) << 13);
    const unsigned short* VtBase = Vt + (((size_t)bh * NITER) << 12) + (lane << 3);

    // ---- prologue: DMA tile (par) -> buf 0; SF tile (par) -> regs ----
    {
        const unsigned short* K0 = KtBase + ((size_t)par << 13);
        #pragma unroll
        for (int i = 0; i < 4; ++i)
            GLOAD16(K0 + (wq * 4 + i) * 512 + lane * 8, &sK[0][par][(wq * 4 + i) * 512]);
    }

    const float* sfq[2];
    f32x4 sf0[2], sf1[2];
    {
        const f32x4 l2e = {LOG2E, LOG2E, LOG2E, LOG2E};
        #pragma unroll
        for (int g = 0; g < 2; ++g) {
            sfq[g] = SF + (size_t)qrow[g] * S_LEN + quad * 4;
            sf0[g] = *(const f32x4*)(sfq[g] + par * 32) * l2e;
            sf1[g] = *(const f32x4*)(sfq[g] + par * 32 + 16) * l2e;
        }
    }

    for (int it = 0; it < NITER2; ++it) {
        const int p = it & 1;
        // Publishes sK[p][*] (vmcnt(0) drain: DMAs issued a full iteration ago).
        // Also guarantees everyone is done reading sK[1-p][*].
        __syncthreads();

        // ---- V(2*it+par) -> registers, issued first (consumed after QK+softmax) ----
        uint4 vreg[8];
        {
            const unsigned short* Vk = VtBase + ((size_t)(2 * it + par) << 12);
            #pragma unroll
            for (int dt = 0; dt < 8; ++dt)
                vreg[dt] = *(const uint4*)(Vk + (dt << 9));
        }

        // ---- prefetch tile (2*it+2+par) into buf[1-p][par]; SF into regs ----
        f32x4 nf0[2], nf1[2];
        const bool more = (it + 1 < NITER2);
        if (more) {
            const unsigned short* Kn = KtBase + ((size_t)(2 * it + 2 + par) << 13);
            #pragma unroll
            for (int i = 0; i < 4; ++i)
                GLOAD16(Kn + (wq * 4 + i) * 512 + lane * 8, &sK[1 - p][par][(wq * 4 + i) * 512]);
            const f32x4 l2e = {LOG2E, LOG2E, LOG2E, LOG2E};
            #pragma unroll
            for (int g = 0; g < 2; ++g) {
                nf0[g] = *(const f32x4*)(sfq[g] + (2 * it + 2 + par) * 32) * l2e;
                nf1[g] = *(const f32x4*)(sfq[g] + (2 * it + 2 + par) * 32 + 16) * l2e;
            }
        }

        // ---- QK^T, swapped operands; each K fragment reused by both q-groups ----
        const unsigned short* sKp = sK[p][par];
        f32x4 acc[2][2] = {};
        __builtin_amdgcn_s_setprio(1);
        #pragma unroll
        for (int nt = 0; nt < 2; ++nt) {
            const unsigned short* rowp = sKp + (nt * 16 + lr) * 256;
            #pragma unroll
            for (int d0 = 0; d0 < 4; ++d0) {
                const int uh = (8 * d0 + 2 * quad) ^ rl;
                const s16x8 kh8 = *(const s16x8*)(rowp + (uh << 3));
                const s16x8 kl8 = *(const s16x8*)(rowp + ((uh ^ 1) << 3));
                #pragma unroll
                for (int g = 0; g < 2; ++g) {
                    acc[g][nt] = __builtin_amdgcn_mfma_f32_16x16x32_bf16(kh8, qlo[g][d0], acc[g][nt], 0, 0, 0);
                    acc[g][nt] = __builtin_amdgcn_mfma_f32_16x16x32_bf16(kl8, qhi[g][d0], acc[g][nt], 0, 0, 0);
                    acc[g][nt] = __builtin_amdgcn_mfma_f32_16x16x32_bf16(kh8, qhi[g][d0], acc[g][nt], 0, 0, 0);
                }
            }
        }
        __builtin_amdgcn_s_setprio(0);

        // ---- online softmax (base-2), lane-local rows + VALU butterflies ----
        union PB { u32 w2[2]; s16x4 v; } B0[2], B1[2];
        #pragma unroll
        for (int g = 0; g < 2; ++g) {
            const f32x4 t0 = acc[g][0] * sf0[g];
            const f32x4 t1 = acc[g][1] * sf1[g];
            float mx = fmaxf(fmaxf(fmaxf(t0[0], t0[1]), fmaxf(t0[2], t0[3])),
                             fmaxf(fmaxf(t1[0], t1[1]), fmaxf(t1[2], t1[3])));
            BFLY(mx, fmaxf);
            const float mnew = fmaxf(mrow[g], mx);
            if (!__all(mnew == mrow[g])) {
                const float al = EXP2(mrow[g] - mnew);
                mrow[g] = mnew;
                lrow[g] *= al;
                const f32x4 alv = {al, al, al, al};
                #pragma unroll
                for (int dt = 0; dt < 8; ++dt)
                    Oacc[g][dt] *= alv;
            }
            const float m = mrow[g];
            f32x4 P0, P1;
            #pragma unroll
            for (int r = 0; r < 4; ++r) {
                P0[r] = EXP2(t0[r] - m);
                P1[r] = EXP2(t1[r] - m);
            }
            float rs = ((P0[0] + P0[1]) + (P0[2] + P0[3])) + ((P1[0] + P1[1]) + (P1[2] + P1[3]));
            BFLY(rs, fadd_);
            lrow[g] += rs;
            B0[g].w2[0] = pack_rne(P0[0], P0[1]); B0[g].w2[1] = pack_rne(P0[2], P0[3]);
            B1[g].w2[0] = pack_rne(P1[0], P1[1]); B1[g].w2[1] = pack_rne(P1[2], P1[3]);
        }

        // ---- P·V from registers; each V fragment reused by both q-groups ----
        __builtin_amdgcn_s_setprio(1);
        #pragma unroll
        for (int dt = 0; dt < 8; ++dt) {
            union { uint4 u; struct { s16x4 a0; s16x4 a1; } s; } vv;
            vv.u = vreg[dt];
            #pragma unroll
            for (int g = 0; g < 2; ++g) {
                Oacc[g][dt] = MFMA16(vv.s.a0, B0[g].v, Oacc[g][dt]);
                Oacc[g][dt] = MFMA16(vv.s.a1, B1[g].v, Oacc[g][dt]);
            }
        }
        __builtin_amdgcn_s_setprio(0);

        if (more) {
            #pragma unroll
            for (int g = 0; g < 2; ++g) { sf0[g] = nf0[g]; sf1[g] = nf1[g]; }
        }
    }

    // ---- epilogue: two-way flash merge (even set combines, odd set publishes) ----
    __syncthreads();   // all K-tile reads done; sK reusable as O buffer
    float* obuf = (float*)&sK[0][0][0];   // 64 KB: [wq][g][dt][lane] f32x4
    if (par) {
        #pragma unroll
        for (int g = 0; g < 2; ++g) {
            mlx[wq][g][lr][0] = mrow[g];   // replicated across quads: same value
            mlx[wq][g][lr][1] = lrow[g];
            #pragma unroll
            for (int dt = 0; dt < 8; ++dt)
                *(f32x4*)(obuf + ((((wq * 2 + g) * 8 + dt) * 64 + lane) << 2)) = Oacc[g][dt];
        }
    }
    __syncthreads();
    if (!par) {
        const float dpf = (float)DP[0];
        #pragma unroll
        for (int g = 0; g < 2; ++g) {
            const float m_o = mlx[wq][g][lr][0];
            const float l_o = mlx[wq][g][lr][1];
            const float ms  = fmaxf(mrow[g], m_o);
            const float se  = EXP2(mrow[g] - ms);
            const float so  = EXP2(m_o - ms);
            const float ls  = se * lrow[g] + so * l_o;
            const float fe  = se * dpf / ls;
            const float fo  = so * dpf / ls;
            const f32x4 fev = {fe, fe, fe, fe};
            const f32x4 fov = {fo, fo, fo, fo};
            float* orow = OUT + bh_off + (size_t)qrow[g] * D_DIM + quad * 4;
            #pragma unroll
            for (int dt = 0; dt < 8; ++dt) {
                const f32x4 oo = *(const f32x4*)(obuf + ((((wq * 2 + g) * 8 + dt) * 64 + lane) << 2));
                const f32x4 o = Oacc[g][dt] * fev + oo * fov;
                *(f32x4*)(orow + dt * 16) = o;
            }
        }
    }
}

extern "C" void kernel_launch(void* const* d_in, const int* in_sizes, int n_in,
                              void* d_out, int out_size, void* d_ws, size_t ws_size,
                              hipStream_t stream) {
    const float* q  = (const float*)d_in[0];
    const float* k  = (const float*)d_in[1];
    const float* v  = (const float*)d_in[2];
    const float* sf = (const float*)d_in[3];
    const int*   dp = (const int*)d_in[4];
    float* out = (float*)d_out;

    const size_t kc_ushorts = (size_t)32 * NITER * 32 * 256;
    unsigned short* Kc = (unsigned short*)d_ws;
    unsigned short* Vt = Kc + kc_ushorts;

    prep_k<<<4096, 256, 0, stream>>>(k, Kc);
    prep_v<<<1024, 256, 0, stream>>>(v, Vt);
    dim3 grid(S_LEN / BQ, 32);   // (16, 32) = 512 blocks of 512 threads, 2/CU
    attn_fused<<<grid, dim3(512), 0, stream>>>(q, Kc, Vt, sf, dp, out);
}